// Round 2
// baseline (347.176 us; speedup 1.0000x reference)
//
#include <hip/hip_runtime.h>

// ---------------------------------------------------------------------------
// Transformer block on MI355X. fp32 I/O (per reference), bf16 MFMA internals,
// fp32 accumulation/residuals.
// R11: 2-phase double-buffered GEMM K-loop (T3-minimum). rocprof R10: FC2
// gemm_bt 67us, MfmaUtil 19% / VALU 20% / HBM 39% / occ 18% -> latency-bound
// on the per-K-step vmcnt(0)+barrier drain, 64 K-steps, only 2 blocks/CU
// (grid-limited) so no implicit cross-block overlap. Fix: issue tile k+1's
// global_load_lds BEFORE computing tile k, wait counted vmcnt(6) (tile k's
// loads only), raw s_barrier (no compiler vmcnt(0) re-drain), lgkmcnt(0)
// before phase-end barrier (WAR vs next stage). FC1 moves BN=128->64 so dbuf
// LDS stays 48KB (3 blocks/CU; 64KB would cap at 2 = m132 regression trap).
// R10 kept: kexp folded into kh, l=P@1 on MFMA pipe, v_cvt_pk_bf16_f32 P,
// bare v_exp_f32. R9 kept: XCD-local flash grid, register-P S^T math.
// ws layout (72 MB preferred / 56 MB fallback):
//   [0,16M)   x1    f32 4096x1024   | during flash: bf16 O-partials x2 (16MB)
//   [16,24M)  hbuf  bf16 LN out     | during flash: l-partials (512 KB)
//   [24,32M)  wT1   bf16 weight^T (w_k^T / w_proj^T / w_fc1^T)
//   [32,40M)  wT2   bf16 w_fc2^T
//   [40,48M)  kh    bf16 [B*H][L][64]   } dead after flash ->
//   [48,56M)  khT   bf16 [B*H][64][L]   }   fc1o 4096x4096 ([40,72M))
// attn (bf16 8MB) lives in d_out (16MB fp32), dead before FC2 writes d_out.
// ---------------------------------------------------------------------------

typedef __attribute__((ext_vector_type(8))) short s8v;  // 8 bf16 raw
typedef __attribute__((ext_vector_type(4))) short s4v;  // 4 bf16 raw
typedef __attribute__((ext_vector_type(4))) float f4v;  // mfma accumulator

#define D_MODEL 1024
#define SEQ 2048
#define BATCH 2
#define NH 16
#define DH 64
#define MROWS (BATCH * SEQ)

// sqrt(0.125 * log2(e)) and its inverse: kh scaled by KH_SCALE => S = qk*kexp
// straight out of the MFMA; O scaled by KH_SCALE, undone in attn_combine.
#define KH_SCALE 0.42466088f
#define KH_ISCALE 2.3548200f

__device__ __forceinline__ float b2f(unsigned short u) {
  union { unsigned int i; float f; } v; v.i = ((unsigned int)u) << 16; return v.f;
}
__device__ __forceinline__ unsigned short f2b(float f) {
  unsigned int i = __builtin_bit_cast(unsigned int, f);
  unsigned int r = (i + 0x7fffu + ((i >> 16) & 1u)) >> 16;  // RNE
  return (unsigned short)r;
}
// async global->LDS, 16B/lane; dest = wave-uniform base + lane*16 (m104/m108)
__device__ __forceinline__ void async16(const void* g, void* l) {
  __builtin_amdgcn_global_load_lds(
      (const __attribute__((address_space(1))) unsigned int*)g,
      (__attribute__((address_space(3))) unsigned int*)l, 16, 0, 0);
}
__device__ __forceinline__ unsigned short cvt_b(float f) { return f2b(f); }
__device__ __forceinline__ unsigned short cvt_b(unsigned short u) { return u; }

// bare v_exp_f32 (exp2); OCML exp2f adds range-check overhead
__device__ __forceinline__ float xp2(float x) {
#if __has_builtin(__builtin_amdgcn_exp2f)
  return __builtin_amdgcn_exp2f(x);
#else
  return exp2f(x);
#endif
}

// 4x f32 -> packed bf16 s4v via v_cvt_pk_bf16_f32 (RNE, 2 instructions).
__device__ __forceinline__ s4v cvt4(float a, float b, float c, float d) {
  unsigned int lo, hi;
  asm("v_cvt_pk_bf16_f32 %0, %1, %2" : "=v"(lo) : "v"(a), "v"(b));
  asm("v_cvt_pk_bf16_f32 %0, %1, %2" : "=v"(hi) : "v"(c), "v"(d));
  union { unsigned long long u; s4v v; } u;
  u.u = ((unsigned long long)hi << 32) | (unsigned long long)lo;
  return u.v;
}

// K=16 bf16 mfma: prefer native; fall back to zero-padded K=32.
#if __has_builtin(__builtin_amdgcn_mfma_f32_16x16x16_bf16)
__device__ __forceinline__ f4v mfma16(s4v a, s4v b, f4v c) {
  return __builtin_amdgcn_mfma_f32_16x16x16_bf16(a, b, c, 0, 0, 0);
}
#elif __has_builtin(__builtin_amdgcn_mfma_f32_16x16x16bf16_1k)
__device__ __forceinline__ f4v mfma16(s4v a, s4v b, f4v c) {
  return __builtin_amdgcn_mfma_f32_16x16x16bf16_1k(a, b, c, 0, 0, 0);
}
#else
__device__ __forceinline__ f4v mfma16(s4v a, s4v b, f4v c) {
  s8v aa = {a[0], a[1], a[2], a[3], 0, 0, 0, 0};
  s8v bb = {b[0], b[1], b[2], b[3], 0, 0, 0, 0};
  return __builtin_amdgcn_mfma_f32_16x16x32_bf16(aa, bb, c, 0, 0, 0);
}
#endif

// ---------------- LayerNorm: fp32 in -> bf16 out, one block per row ---------
__global__ __launch_bounds__(256) void ln_kernel(
    const float* __restrict__ x, const float* __restrict__ g,
    const float* __restrict__ bb, unsigned short* __restrict__ out) {
  int row = blockIdx.x;
  int t = threadIdx.x;
  const float* xr = x + (size_t)row * D_MODEL;
  float v[4];
  float s = 0.f, s2 = 0.f;
#pragma unroll
  for (int i = 0; i < 4; ++i) {
    float f = xr[t + 256 * i];
    v[i] = f; s += f; s2 += f * f;
  }
#pragma unroll
  for (int off = 1; off < 64; off <<= 1) {
    s += __shfl_xor(s, off, 64);
    s2 += __shfl_xor(s2, off, 64);
  }
  __shared__ float red[8];
  if ((t & 63) == 0) { red[t >> 6] = s; red[4 + (t >> 6)] = s2; }
  __syncthreads();
  s = red[0] + red[1] + red[2] + red[3];
  s2 = red[4] + red[5] + red[6] + red[7];
  float mu = s * (1.f / D_MODEL);
  float var = s2 * (1.f / D_MODEL) - mu * mu;
  float rstd = rsqrtf(var + 1e-5f);
#pragma unroll
  for (int i = 0; i < 4; ++i) {
    int c = t + 256 * i;
    float h = (v[i] - mu) * rstd * g[c] + bb[c];
    out[(size_t)row * D_MODEL + c] = f2b(h);
  }
}

// ---------------- batched 64x64 tile transpose -> bf16 ----------------------
template <typename T>
__global__ __launch_bounds__(256) void transpose_b(
    const T* __restrict__ src, unsigned short* __restrict__ dst,
    int srcStride, int dstStride, long long srcBatch, long long dstBatch) {
  __shared__ unsigned short tile[64][65];
  const T* s = src + (size_t)blockIdx.z * srcBatch;
  unsigned short* d = dst + (size_t)blockIdx.z * dstBatch;
  int n0 = blockIdx.x * 64, k0 = blockIdx.y * 64;
  for (int i = threadIdx.x; i < 4096; i += 256) {
    int k = i >> 6, n = i & 63;
    tile[k][n] = cvt_b(s[(size_t)(k0 + k) * srcStride + n0 + n]);
  }
  __syncthreads();
  for (int i = threadIdx.x; i < 4096; i += 256) {
    int n = i >> 6, k = i & 63;
    d[(size_t)(n0 + n) * dstStride + k0 + k] = tile[k][n];
  }
}

// ---------------- GEMM: C[M,N] = A[M,K] @ Bt[N,K]^T + bias (+res)(+relu) ----
// 128xBN tile (BN=64), BK=64, 4 waves (2x2) each 64x(BN/2).
// R11: 2-phase double-buffered staging. Stage tile kt+1 into buf^1 BEFORE
// computing tile kt; counted vmcnt (6 loads/wave in flight for next tile),
// raw s_barrier so the compiler cannot re-insert a vmcnt(0) drain.
// LDS [row][64] bf16 with 16B-chunk XOR swizzle; global_load_lds width=16.
// KH path additionally scales output by KH_SCALE (softmax pre-scale, R10).
template <int RES, bool RELU, bool KH, int OUTF, int BN>
__global__ __launch_bounds__(256) void gemm_bt(
    const unsigned short* __restrict__ A, const unsigned short* __restrict__ Bt,
    const float* __restrict__ bias, const float* __restrict__ res,
    void* __restrict__ out, int M, int N, int K) {
  constexpr int NT = BN / 32;  // N frag-tiles per wave
  __shared__ __align__(16) unsigned short lsA[2][128 * 64];
  __shared__ __align__(16) unsigned short lsB[2][BN * 64];
  int tid = threadIdx.x;
  int lane = tid & 63, w = tid >> 6, quad = lane >> 4, l16 = lane & 15;
  int m0 = blockIdx.y * 128, n0 = blockIdx.x * BN;
  int wm = (w >> 1) * 64, wn = (w & 1) * (BN / 2);
  f4v acc[4][NT] = {};

  // issue one K-tile's staging loads (async, 4 + BN/32 per wave)
  auto stage = [&](int bsel, int ktE) {
#pragma unroll
    for (int i = 0; i < 4; ++i) {
      int cb = w * 256 + i * 64;
      int ci = cb + lane;
      int row = ci >> 3, c = ci & 7;
      int cs = c ^ (row & 7);
      async16(A + (size_t)(m0 + row) * K + ktE + cs * 8, &lsA[bsel][cb * 8]);
    }
#pragma unroll
    for (int i = 0; i < BN / 32; ++i) {
      int cb = w * (BN * 2) + i * 64;
      int ci = cb + lane;
      int row = ci >> 3, c = ci & 7;
      int cs = c ^ (row & 7);
      async16(Bt + (size_t)(n0 + row) * K + ktE + cs * 8, &lsB[bsel][cb * 8]);
    }
  };

  stage(0, 0);
  int nK = K >> 6;
  for (int kt = 0; kt < nK; ++kt) {
    int b = kt & 1;
    if (kt + 1 < nK) {
      stage(b ^ 1, (kt + 1) << 6);  // prefetch next tile (stays in flight)
      if constexpr (BN == 64) asm volatile("s_waitcnt vmcnt(6)" ::: "memory");
      else                    asm volatile("s_waitcnt vmcnt(8)" ::: "memory");
    } else {
      asm volatile("s_waitcnt vmcnt(0)" ::: "memory");
    }
    __builtin_amdgcn_sched_barrier(0);
    __builtin_amdgcn_s_barrier();   // all waves' tile-kt loads landed
    __builtin_amdgcn_sched_barrier(0);
#pragma unroll
    for (int s = 0; s < 2; ++s) {
      s8v af[4], bf[NT];
#pragma unroll
      for (int t = 0; t < 4; ++t) {
        int am = wm + t * 16 + l16;
        int ac = (s * 4 + quad) ^ (am & 7);
        af[t] = *(const s8v*)(&lsA[b][am * 64 + ac * 8]);
      }
#pragma unroll
      for (int t = 0; t < NT; ++t) {
        int bn = wn + t * 16 + l16;
        int bc = (s * 4 + quad) ^ (bn & 7);
        bf[t] = *(const s8v*)(&lsB[b][bn * 64 + bc * 8]);
      }
#pragma unroll
      for (int ti = 0; ti < 4; ++ti)
#pragma unroll
        for (int tj = 0; tj < NT; ++tj)
          acc[ti][tj] = __builtin_amdgcn_mfma_f32_16x16x32_bf16(
              af[ti], bf[tj], acc[ti][tj], 0, 0, 0);
    }
    // WAR: my ds_reads of buf b must complete before others overwrite it
    asm volatile("s_waitcnt lgkmcnt(0)" ::: "memory");
    __builtin_amdgcn_sched_barrier(0);
    __builtin_amdgcn_s_barrier();
    __builtin_amdgcn_sched_barrier(0);
  }
  // epilogue: C/D layout col=lane&15, row=quad*4+r  (m89/m91-verified)
#pragma unroll
  for (int tj = 0; tj < NT; ++tj) {
    int col = n0 + wn + tj * 16 + l16;
    float bv = bias[col];
#pragma unroll
    for (int ti = 0; ti < 4; ++ti) {
#pragma unroll
      for (int r = 0; r < 4; ++r) {
        int rowg = m0 + wm + ti * 16 + quad * 4 + r;
        float vv = acc[ti][tj][r] + bv;
        if (KH) vv *= KH_SCALE;  // pre-scale S by kexp (R10)
        if (RES == 2) vv += res[(size_t)rowg * N + col];
        if (RELU) vv = fmaxf(vv, 0.f);
        size_t oidx;
        if (KH) {
          int b2 = rowg >> 11, l = rowg & 2047, h = col >> 6, d = col & 63;
          oidx = (((size_t)(b2 * NH + h)) * SEQ + l) * DH + d;
        } else {
          oidx = (size_t)rowg * N + col;
        }
        if (OUTF == 0) ((unsigned short*)out)[oidx] = f2b(vv);
        else           ((float*)out)[oidx] = vv;
      }
    }
  }
}

// ---------------- fused flash attention, register-P, XCD-local --------------
// grid (split=2, bh=32, qb=16): linear id = 64*qb + 2*bh + split => id%8 =
// (2bh+split)%8 -> all qb-blocks of a (bh,split) pair share an XCD; per-XCD
// working set = 8 pairs x 256KB = 2MB <= 4MB L2.
// 128-key staging tiles (8 vmcnt stalls/block), processed as 2x64-key halves.
// S^T = mfma(K,Q): exp'd C-frag IS a K=16 A-operand (register P, no LDS trip).
// R10: kh pre-scaled by sqrt(kexp) => exp2 directly on accST; P->bf16 via
// v_cvt_pk_bf16_f32; l = P @ ones on the MFMA pipe (accL).
__global__ __launch_bounds__(256) void flash_k(
    const unsigned short* __restrict__ kh, const unsigned short* __restrict__ khT,
    unsigned short* __restrict__ Opart, float* __restrict__ lpart) {
  __shared__ __align__(16) unsigned short lsK[128 * 64];   // [key][d], 8-chunk rows
  __shared__ __align__(16) unsigned short lsKT[64 * 128];  // [d][key], 16-chunk rows
  int tid = threadIdx.x;
  int lane = tid & 63, w = tid >> 6, quad = lane >> 4, l16 = lane & 15;
  int split = blockIdx.x, bh = blockIdx.y, qb = blockIdx.z;
  const unsigned short* khB = kh + (size_t)bh * SEQ * DH;
  const unsigned short* khTB = khT + (size_t)bh * DH * SEQ;
  unsigned short* Op = Opart + (size_t)split * MROWS * D_MODEL;
  float* lp = lpart + (size_t)split * BATCH * NH * SEQ;
  s8v aQ[2][2];
#pragma unroll
  for (int g = 0; g < 2; ++g) {
    int q = qb * 128 + w * 32 + g * 16 + l16;
#pragma unroll
    for (int s = 0; s < 2; ++s)
      aQ[g][s] = *(const s8v*)(khB + (size_t)q * DH + s * 32 + quad * 8);
  }
  const s4v vone = {(short)0x3F80, (short)0x3F80, (short)0x3F80, (short)0x3F80};
  f4v accO[2][4] = {};
  f4v accL[2] = {};  // row q = quad*4+r (col-replicated): l-sums via MFMA

  for (int kt8 = 0; kt8 < 8; ++kt8) {
    int key0 = split * 1024 + kt8 * 128;
    // stage lsK (128 keys x 64 d): 1024 chunks, 4 async16/wave
#pragma unroll
    for (int i = 0; i < 4; ++i) {
      int cb = w * 256 + i * 64;
      int ci = cb + lane;
      int row = ci >> 3, c = ci & 7;
      int cs = c ^ (row & 7);
      async16(khB + (size_t)(key0 + row) * DH + cs * 8, &lsK[cb * 8]);
    }
    // stage lsKT (64 d x 128 keys): 1024 chunks, 16-slot swizzle
#pragma unroll
    for (int i = 0; i < 4; ++i) {
      int cb = w * 256 + i * 64;
      int ci = cb + lane;
      int row = ci >> 4, c = ci & 15;
      int cs = c ^ (row & 15);
      async16(khTB + (size_t)row * SEQ + key0 + cs * 8, &lsKT[cb * 8]);
    }
    __builtin_amdgcn_s_waitcnt(0x0f70);  // vmcnt(0)
    __syncthreads();
#pragma unroll
    for (int half = 0; half < 2; ++half) {
      // S^T = K @ Q^T over 64 keys (lane = key within sub-tile)
      f4v accST[2][4] = {};
#pragma unroll
      for (int s = 0; s < 2; ++s) {
#pragma unroll
        for (int tj = 0; tj < 4; ++tj) {
          int key = half * 64 + tj * 16 + l16;
          int c = (s * 4 + quad) ^ (key & 7);
          s8v kf = *(const s8v*)(&lsK[key * 64 + c * 8]);
#pragma unroll
          for (int g = 0; g < 2; ++g)
            accST[g][tj] = __builtin_amdgcn_mfma_f32_16x16x32_bf16(
                kf, aQ[g][s], accST[g][tj], 0, 0, 0);
        }
      }
      // exp in-register -> P A-frags (cvt_pk RNE); l via MFMA; PV from lsKT
#pragma unroll
      for (int tj = 0; tj < 4; ++tj) {
        s4v pf[2];
#pragma unroll
        for (int g = 0; g < 2; ++g) {
          float p0 = xp2(accST[g][tj][0]);
          float p1 = xp2(accST[g][tj][1]);
          float p2 = xp2(accST[g][tj][2]);
          float p3 = xp2(accST[g][tj][3]);
          pf[g] = cvt4(p0, p1, p2, p3);
          accL[g] = mfma16(pf[g], vone, accL[g]);  // l-sum on MFMA pipe
        }
#pragma unroll
        for (int db = 0; db < 4; ++db) {
          int d = db * 16 + l16;
          int ch = (half * 8 + tj * 2 + (quad >> 1)) ^ (d & 15);
          s4v vf = *(const s4v*)(&lsKT[d * 128 + ch * 8 + (quad & 1) * 4]);
#pragma unroll
          for (int g = 0; g < 2; ++g)
            accO[g][db] = mfma16(pf[g], vf, accO[g][db]);
        }
      }
    }
    __syncthreads();
  }
  // epilogue: accL rows = q (quad*4+r), cols replicated -> l16==0 lanes write
  int b = bh >> 4, h = bh & 15;
#pragma unroll
  for (int g = 0; g < 2; ++g) {
    if (l16 == 0) {
#pragma unroll
      for (int r = 0; r < 4; ++r) {
        int q = qb * 128 + w * 32 + g * 16 + quad * 4 + r;
        lp[(size_t)bh * SEQ + q] = accL[g][r];
      }
    }
#pragma unroll
    for (int r = 0; r < 4; ++r) {
      int l = qb * 128 + w * 32 + g * 16 + quad * 4 + r;
#pragma unroll
      for (int db = 0; db < 4; ++db) {
        int d = db * 16 + l16;
        Op[((size_t)(b * SEQ + l)) * D_MODEL + h * DH + d] = f2b(accO[g][db][r]);
      }
    }
  }
}

// ---------------- combine: attn = (O0+O1)/(l0+l1), bf16 partials ------------
// R10: O partials carry the KH_SCALE V-scale; undo with KH_ISCALE here.
__global__ __launch_bounds__(256) void attn_combine(
    const unsigned short* __restrict__ Opart, const float* __restrict__ lpart,
    unsigned short* __restrict__ attn) {
  int row = blockIdx.x;  // b*SEQ + l
  int b = row >> 11, l = row & 2047;
  int c0 = threadIdx.x * 4;
  int h = c0 >> 6;
  size_t lidx = (size_t)(b * NH + h) * SEQ + l;
  float ls = lpart[lidx] + lpart[(size_t)BATCH * NH * SEQ + lidx];
  float inv = KH_ISCALE / ls;
  s4v o0 = *(const s4v*)(Opart + (size_t)row * D_MODEL + c0);
  s4v o1 = *(const s4v*)(Opart + (size_t)MROWS * D_MODEL +
                         (size_t)row * D_MODEL + c0);
  s4v ov;
#pragma unroll
  for (int i = 0; i < 4; ++i)
    ov[i] = (short)f2b((b2f((unsigned short)o0[i]) +
                        b2f((unsigned short)o1[i])) * inv);
  *(s4v*)(attn + (size_t)row * D_MODEL + c0) = ov;
}

// ---------------------------------------------------------------------------
extern "C" void kernel_launch(void* const* d_in, const int* in_sizes, int n_in,
                              void* d_out, int out_size, void* d_ws, size_t ws_size,
                              hipStream_t stream) {
  (void)in_sizes; (void)n_in; (void)out_size;
  const float* x      = (const float*)d_in[0];
  const float* w_attn = (const float*)d_in[1];
  const float* b_attn = (const float*)d_in[2];
  const float* w_proj = (const float*)d_in[3];
  const float* b_proj = (const float*)d_in[4];
  const float* ln1_g  = (const float*)d_in[5];
  const float* ln1_b  = (const float*)d_in[6];
  const float* ln2_g  = (const float*)d_in[7];
  const float* ln2_b  = (const float*)d_in[8];
  const float* w_fc1  = (const float*)d_in[9];
  const float* b_fc1  = (const float*)d_in[10];
  const float* w_fc2  = (const float*)d_in[11];
  const float* b_fc2  = (const float*)d_in[12];

  char* ws = (char*)d_ws;
  float*          x1    = (float*)(ws);                                // 16MB
  unsigned short* hbuf  = (unsigned short*)(ws + (size_t)(16u << 20)); // 8MB
  unsigned short* wT1   = (unsigned short*)(ws + (size_t)(24u << 20)); // 8MB
  unsigned short* wT2   = (unsigned short*)(ws + (size_t)(32u << 20)); // 8MB
  unsigned short* kh    = (unsigned short*)(ws + (size_t)(40u << 20)); // 8MB
  unsigned short* khT   = (unsigned short*)(ws + (size_t)(48u << 20)); // 8MB
  unsigned short* Opart = (unsigned short*)(ws);   // [0,16M) during flash
  float*          lpart = (float*)(ws + (size_t)(16u << 20));  // 512KB, hbuf dead
  unsigned short* fc1o  = kh;  // overlays kh/khT (+tail if unchunked)
  unsigned short* attn  = (unsigned short*)d_out;  // scratch, dead pre-FC2
  float* outf = (float*)d_out;
  bool big_ws = ws_size >= ((size_t)72u << 20);

  dim3 blk(256);
  // 1. h1 = LN1(x)
  hipLaunchKernelGGL(ln_kernel, dim3(MROWS), blk, 0, stream, x, ln1_g, ln1_b, hbuf);
  // 2. wT1 = (w_attn[:, 1024:2048])^T  (only the K slice is ever used)
  hipLaunchKernelGGL(transpose_b<float>, dim3(16, 16, 1), blk, 0, stream,
                     w_attn + 1024, wT1, 3 * D_MODEL, D_MODEL, 0LL, 0LL);
  // 3. kh[b,h,l,d] = (h1 @ w_k + b_k) * KH_SCALE   (BN=64 -> 512 blocks)
  hipLaunchKernelGGL((gemm_bt<0, false, true, 0, 64>), dim3(16, 32), blk, 0, stream,
                     hbuf, wT1, b_attn + 1024, nullptr, (void*)kh,
                     MROWS, D_MODEL, D_MODEL);
  // 4. khT[b,h,d,l] = transpose(kh) per head
  hipLaunchKernelGGL(transpose_b<unsigned short>, dim3(1, 32, 32), blk, 0, stream,
                     kh, khT, DH, SEQ, (long long)(SEQ * DH), (long long)(DH * SEQ));
  // 5. flash (XCD-local grid) -> bf16 unnormalized partials; combine -> attn
  hipLaunchKernelGGL(flash_k, dim3(2, 32, SEQ / 128), blk, 0, stream,
                     kh, khT, Opart, lpart);
  hipLaunchKernelGGL(attn_combine, dim3(MROWS), blk, 0, stream,
                     Opart, lpart, attn);
  // 6. wT1 = w_proj^T
  hipLaunchKernelGGL(transpose_b<float>, dim3(16, 16, 1), blk, 0, stream,
                     w_proj, wT1, D_MODEL, D_MODEL, 0LL, 0LL);
  // 7. x1 = x + attn @ w_proj + b_proj   (fp32, BN=64)
  hipLaunchKernelGGL((gemm_bt<2, false, false, 1, 64>), dim3(16, 32), blk, 0, stream,
                     attn, wT1, b_proj, x, (void*)x1, MROWS, D_MODEL, D_MODEL);
  // 8. h2 = LN2(x1)
  hipLaunchKernelGGL(ln_kernel, dim3(MROWS), blk, 0, stream, x1, ln2_g, ln2_b, hbuf);
  // 9. wT1 = w_fc1^T ; wT2 = w_fc2^T
  hipLaunchKernelGGL(transpose_b<float>, dim3(64, 16, 1), blk, 0, stream,
                     w_fc1, wT1, 4 * D_MODEL, D_MODEL, 0LL, 0LL);
  hipLaunchKernelGGL(transpose_b<float>, dim3(16, 64, 1), blk, 0, stream,
                     w_fc2, wT2, D_MODEL, 4 * D_MODEL, 0LL, 0LL);
  // 10. FFN: FC1 BN=64 (2048 blocks, dbuf); FC2 BN=64 (512 blocks, dbuf)
  if (big_ws) {
    hipLaunchKernelGGL((gemm_bt<0, true, false, 0, 64>), dim3(64, 32), blk, 0, stream,
                       hbuf, wT1, b_fc1, nullptr, (void*)fc1o,
                       MROWS, 4 * D_MODEL, D_MODEL);
    hipLaunchKernelGGL((gemm_bt<2, false, false, 1, 64>), dim3(16, 32), blk, 0, stream,
                       fc1o, wT2, b_fc2, x1, (void*)outf,
                       MROWS, D_MODEL, 4 * D_MODEL);
  } else {
    for (int c = 0; c < 2; ++c) {
      const unsigned short* h2c = hbuf + (size_t)c * 2048 * D_MODEL;
      const float* x1c = x1 + (size_t)c * 2048 * D_MODEL;
      float* outc = outf + (size_t)c * 2048 * D_MODEL;
      hipLaunchKernelGGL((gemm_bt<0, true, false, 0, 64>), dim3(64, 16), blk, 0, stream,
                         h2c, wT1, b_fc1, nullptr, (void*)fc1o,
                         2048, 4 * D_MODEL, D_MODEL);
      hipLaunchKernelGGL((gemm_bt<2, false, false, 1, 64>), dim3(16, 16), blk, 0, stream,
                         fc1o, wT2, b_fc2, x1c, (void*)outc,
                         2048, D_MODEL, 4 * D_MODEL);
    }
  }
}

// Round 3
// 339.829 us; speedup vs baseline: 1.0216x; 1.0216x over previous
//
#include <hip/hip_runtime.h>

// ---------------------------------------------------------------------------
// Transformer block on MI355X. fp32 I/O (per reference), bf16 MFMA internals,
// fp32 accumulation/residuals.
// R12: BM=64 tiles for the N=1024 GEMMs (kh, proj, FC2). R11 post-mortem:
// dbuf+counted-vmcnt cut VALUBusy 20->15% but duration flat; counters show
// everything at ~30% (MFMA 20, L2 34, HBM 31, LDS 35) = serialized phases at
// 2 blocks/CU (512-block grid, 19% occ) with nothing to overlap across.
// Fix: 64x64 tiles -> 1024 blocks = 4 blocks/CU, 16 waves/CU, 2x TLP;
// LDS 32KB/block so 4 blocks fit. FC1 (2048 blocks already) keeps BM=128.
// R11 kept: 2-phase dbuf, counted vmcnt (BM/32+BN/32), raw s_barrier.
// R10 kept: kexp folded into kh, l=P@1 on MFMA pipe, v_cvt_pk_bf16_f32,
// bare v_exp_f32. R9 kept: XCD-local flash grid, register-P S^T math.
// ws layout (72 MB preferred / 56 MB fallback):
//   [0,16M)   x1    f32 4096x1024   | during flash: bf16 O-partials x2 (16MB)
//   [16,24M)  hbuf  bf16 LN out     | during flash: l-partials (512 KB)
//   [24,32M)  wT1   bf16 weight^T (w_k^T / w_proj^T / w_fc1^T)
//   [32,40M)  wT2   bf16 w_fc2^T
//   [40,48M)  kh    bf16 [B*H][L][64]   } dead after flash ->
//   [48,56M)  khT   bf16 [B*H][64][L]   }   fc1o 4096x4096 ([40,72M))
// attn (bf16 8MB) lives in d_out (16MB fp32), dead before FC2 writes d_out.
// ---------------------------------------------------------------------------

typedef __attribute__((ext_vector_type(8))) short s8v;  // 8 bf16 raw
typedef __attribute__((ext_vector_type(4))) short s4v;  // 4 bf16 raw
typedef __attribute__((ext_vector_type(4))) float f4v;  // mfma accumulator

#define D_MODEL 1024
#define SEQ 2048
#define BATCH 2
#define NH 16
#define DH 64
#define MROWS (BATCH * SEQ)

// sqrt(0.125 * log2(e)) and its inverse: kh scaled by KH_SCALE => S = qk*kexp
// straight out of the MFMA; O scaled by KH_SCALE, undone in attn_combine.
#define KH_SCALE 0.42466088f
#define KH_ISCALE 2.3548200f

__device__ __forceinline__ float b2f(unsigned short u) {
  union { unsigned int i; float f; } v; v.i = ((unsigned int)u) << 16; return v.f;
}
__device__ __forceinline__ unsigned short f2b(float f) {
  unsigned int i = __builtin_bit_cast(unsigned int, f);
  unsigned int r = (i + 0x7fffu + ((i >> 16) & 1u)) >> 16;  // RNE
  return (unsigned short)r;
}
// async global->LDS, 16B/lane; dest = wave-uniform base + lane*16 (m104/m108)
__device__ __forceinline__ void async16(const void* g, void* l) {
  __builtin_amdgcn_global_load_lds(
      (const __attribute__((address_space(1))) unsigned int*)g,
      (__attribute__((address_space(3))) unsigned int*)l, 16, 0, 0);
}
__device__ __forceinline__ unsigned short cvt_b(float f) { return f2b(f); }
__device__ __forceinline__ unsigned short cvt_b(unsigned short u) { return u; }

// bare v_exp_f32 (exp2); OCML exp2f adds range-check overhead
__device__ __forceinline__ float xp2(float x) {
#if __has_builtin(__builtin_amdgcn_exp2f)
  return __builtin_amdgcn_exp2f(x);
#else
  return exp2f(x);
#endif
}

// 4x f32 -> packed bf16 s4v via v_cvt_pk_bf16_f32 (RNE, 2 instructions).
__device__ __forceinline__ s4v cvt4(float a, float b, float c, float d) {
  unsigned int lo, hi;
  asm("v_cvt_pk_bf16_f32 %0, %1, %2" : "=v"(lo) : "v"(a), "v"(b));
  asm("v_cvt_pk_bf16_f32 %0, %1, %2" : "=v"(hi) : "v"(c), "v"(d));
  union { unsigned long long u; s4v v; } u;
  u.u = ((unsigned long long)hi << 32) | (unsigned long long)lo;
  return u.v;
}

// K=16 bf16 mfma: prefer native; fall back to zero-padded K=32.
#if __has_builtin(__builtin_amdgcn_mfma_f32_16x16x16_bf16)
__device__ __forceinline__ f4v mfma16(s4v a, s4v b, f4v c) {
  return __builtin_amdgcn_mfma_f32_16x16x16_bf16(a, b, c, 0, 0, 0);
}
#elif __has_builtin(__builtin_amdgcn_mfma_f32_16x16x16bf16_1k)
__device__ __forceinline__ f4v mfma16(s4v a, s4v b, f4v c) {
  return __builtin_amdgcn_mfma_f32_16x16x16bf16_1k(a, b, c, 0, 0, 0);
}
#else
__device__ __forceinline__ f4v mfma16(s4v a, s4v b, f4v c) {
  s8v aa = {a[0], a[1], a[2], a[3], 0, 0, 0, 0};
  s8v bb = {b[0], b[1], b[2], b[3], 0, 0, 0, 0};
  return __builtin_amdgcn_mfma_f32_16x16x32_bf16(aa, bb, c, 0, 0, 0);
}
#endif

// ---------------- LayerNorm: fp32 in -> bf16 out, one block per row ---------
__global__ __launch_bounds__(256) void ln_kernel(
    const float* __restrict__ x, const float* __restrict__ g,
    const float* __restrict__ bb, unsigned short* __restrict__ out) {
  int row = blockIdx.x;
  int t = threadIdx.x;
  const float* xr = x + (size_t)row * D_MODEL;
  float v[4];
  float s = 0.f, s2 = 0.f;
#pragma unroll
  for (int i = 0; i < 4; ++i) {
    float f = xr[t + 256 * i];
    v[i] = f; s += f; s2 += f * f;
  }
#pragma unroll
  for (int off = 1; off < 64; off <<= 1) {
    s += __shfl_xor(s, off, 64);
    s2 += __shfl_xor(s2, off, 64);
  }
  __shared__ float red[8];
  if ((t & 63) == 0) { red[t >> 6] = s; red[4 + (t >> 6)] = s2; }
  __syncthreads();
  s = red[0] + red[1] + red[2] + red[3];
  s2 = red[4] + red[5] + red[6] + red[7];
  float mu = s * (1.f / D_MODEL);
  float var = s2 * (1.f / D_MODEL) - mu * mu;
  float rstd = rsqrtf(var + 1e-5f);
#pragma unroll
  for (int i = 0; i < 4; ++i) {
    int c = t + 256 * i;
    float h = (v[i] - mu) * rstd * g[c] + bb[c];
    out[(size_t)row * D_MODEL + c] = f2b(h);
  }
}

// ---------------- batched 64x64 tile transpose -> bf16 ----------------------
template <typename T>
__global__ __launch_bounds__(256) void transpose_b(
    const T* __restrict__ src, unsigned short* __restrict__ dst,
    int srcStride, int dstStride, long long srcBatch, long long dstBatch) {
  __shared__ unsigned short tile[64][65];
  const T* s = src + (size_t)blockIdx.z * srcBatch;
  unsigned short* d = dst + (size_t)blockIdx.z * dstBatch;
  int n0 = blockIdx.x * 64, k0 = blockIdx.y * 64;
  for (int i = threadIdx.x; i < 4096; i += 256) {
    int k = i >> 6, n = i & 63;
    tile[k][n] = cvt_b(s[(size_t)(k0 + k) * srcStride + n0 + n]);
  }
  __syncthreads();
  for (int i = threadIdx.x; i < 4096; i += 256) {
    int n = i >> 6, k = i & 63;
    d[(size_t)(n0 + n) * dstStride + k0 + k] = tile[k][n];
  }
}

// ---------------- GEMM: C[M,N] = A[M,K] @ Bt[N,K]^T + bias (+res)(+relu) ----
// BMxBN tile, BK=64, 4 waves (2x2) each (BM/2)x(BN/2).
// R11: 2-phase dbuf staging, counted vmcnt (BM/32+BN/32 loads/wave in
// flight for next tile), raw s_barrier (no compiler vmcnt(0) re-drain).
// R12: BM=64 variant -> 2x grid for N=1024 GEMMs (occupancy 19->38%).
// LDS [row][64] bf16 with 16B-chunk XOR swizzle; global_load_lds width=16.
// KH path additionally scales output by KH_SCALE (softmax pre-scale, R10).
template <int RES, bool RELU, bool KH, int OUTF, int BM, int BN>
__global__ __launch_bounds__(256) void gemm_bt(
    const unsigned short* __restrict__ A, const unsigned short* __restrict__ Bt,
    const float* __restrict__ bias, const float* __restrict__ res,
    void* __restrict__ out, int M, int N, int K) {
  constexpr int MT = BM / 32;  // M frag-tiles per wave
  constexpr int NT = BN / 32;  // N frag-tiles per wave
  __shared__ __align__(16) unsigned short lsA[2][BM * 64];
  __shared__ __align__(16) unsigned short lsB[2][BN * 64];
  int tid = threadIdx.x;
  int lane = tid & 63, w = tid >> 6, quad = lane >> 4, l16 = lane & 15;
  int m0 = blockIdx.y * BM, n0 = blockIdx.x * BN;
  int wm = (w >> 1) * (BM / 2), wn = (w & 1) * (BN / 2);
  f4v acc[MT][NT] = {};

  // issue one K-tile's staging loads (async, MT + NT async16 per wave)
  auto stage = [&](int bsel, int ktE) {
#pragma unroll
    for (int i = 0; i < MT; ++i) {
      int cb = w * (BM * 2) + i * 64;
      int ci = cb + lane;
      int row = ci >> 3, c = ci & 7;
      int cs = c ^ (row & 7);
      async16(A + (size_t)(m0 + row) * K + ktE + cs * 8, &lsA[bsel][cb * 8]);
    }
#pragma unroll
    for (int i = 0; i < NT; ++i) {
      int cb = w * (BN * 2) + i * 64;
      int ci = cb + lane;
      int row = ci >> 3, c = ci & 7;
      int cs = c ^ (row & 7);
      async16(Bt + (size_t)(n0 + row) * K + ktE + cs * 8, &lsB[bsel][cb * 8]);
    }
  };

  stage(0, 0);
  int nK = K >> 6;
  for (int kt = 0; kt < nK; ++kt) {
    int b = kt & 1;
    if (kt + 1 < nK) {
      stage(b ^ 1, (kt + 1) << 6);  // prefetch next tile (stays in flight)
      if constexpr (MT + NT == 4)      asm volatile("s_waitcnt vmcnt(4)" ::: "memory");
      else if constexpr (MT + NT == 6) asm volatile("s_waitcnt vmcnt(6)" ::: "memory");
      else                             asm volatile("s_waitcnt vmcnt(8)" ::: "memory");
    } else {
      asm volatile("s_waitcnt vmcnt(0)" ::: "memory");
    }
    __builtin_amdgcn_sched_barrier(0);
    __builtin_amdgcn_s_barrier();   // all waves' tile-kt loads landed
    __builtin_amdgcn_sched_barrier(0);
#pragma unroll
    for (int s = 0; s < 2; ++s) {
      s8v af[MT], bf[NT];
#pragma unroll
      for (int t = 0; t < MT; ++t) {
        int am = wm + t * 16 + l16;
        int ac = (s * 4 + quad) ^ (am & 7);
        af[t] = *(const s8v*)(&lsA[b][am * 64 + ac * 8]);
      }
#pragma unroll
      for (int t = 0; t < NT; ++t) {
        int bn = wn + t * 16 + l16;
        int bc = (s * 4 + quad) ^ (bn & 7);
        bf[t] = *(const s8v*)(&lsB[b][bn * 64 + bc * 8]);
      }
#pragma unroll
      for (int ti = 0; ti < MT; ++ti)
#pragma unroll
        for (int tj = 0; tj < NT; ++tj)
          acc[ti][tj] = __builtin_amdgcn_mfma_f32_16x16x32_bf16(
              af[ti], bf[tj], acc[ti][tj], 0, 0, 0);
    }
    // WAR: my ds_reads of buf b must complete before others overwrite it
    asm volatile("s_waitcnt lgkmcnt(0)" ::: "memory");
    __builtin_amdgcn_sched_barrier(0);
    __builtin_amdgcn_s_barrier();
    __builtin_amdgcn_sched_barrier(0);
  }
  // epilogue: C/D layout col=lane&15, row=quad*4+r  (m89/m91-verified)
#pragma unroll
  for (int tj = 0; tj < NT; ++tj) {
    int col = n0 + wn + tj * 16 + l16;
    float bv = bias[col];
#pragma unroll
    for (int ti = 0; ti < MT; ++ti) {
#pragma unroll
      for (int r = 0; r < 4; ++r) {
        int rowg = m0 + wm + ti * 16 + quad * 4 + r;
        float vv = acc[ti][tj][r] + bv;
        if (KH) vv *= KH_SCALE;  // pre-scale S by kexp (R10)
        if (RES == 2) vv += res[(size_t)rowg * N + col];
        if (RELU) vv = fmaxf(vv, 0.f);
        size_t oidx;
        if (KH) {
          int b2 = rowg >> 11, l = rowg & 2047, h = col >> 6, d = col & 63;
          oidx = (((size_t)(b2 * NH + h)) * SEQ + l) * DH + d;
        } else {
          oidx = (size_t)rowg * N + col;
        }
        if (OUTF == 0) ((unsigned short*)out)[oidx] = f2b(vv);
        else           ((float*)out)[oidx] = vv;
      }
    }
  }
}

// ---------------- fused flash attention, register-P, XCD-local --------------
// grid (split=2, bh=32, qb=16): linear id = 64*qb + 2*bh + split => id%8 =
// (2bh+split)%8 -> all qb-blocks of a (bh,split) pair share an XCD; per-XCD
// working set = 8 pairs x 256KB = 2MB <= 4MB L2.
// 128-key staging tiles (8 vmcnt stalls/block), processed as 2x64-key halves.
// S^T = mfma(K,Q): exp'd C-frag IS a K=16 A-operand (register P, no LDS trip).
// R10: kh pre-scaled by sqrt(kexp) => exp2 directly on accST; P->bf16 via
// v_cvt_pk_bf16_f32; l = P @ ones on the MFMA pipe (accL).
__global__ __launch_bounds__(256) void flash_k(
    const unsigned short* __restrict__ kh, const unsigned short* __restrict__ khT,
    unsigned short* __restrict__ Opart, float* __restrict__ lpart) {
  __shared__ __align__(16) unsigned short lsK[128 * 64];   // [key][d], 8-chunk rows
  __shared__ __align__(16) unsigned short lsKT[64 * 128];  // [d][key], 16-chunk rows
  int tid = threadIdx.x;
  int lane = tid & 63, w = tid >> 6, quad = lane >> 4, l16 = lane & 15;
  int split = blockIdx.x, bh = blockIdx.y, qb = blockIdx.z;
  const unsigned short* khB = kh + (size_t)bh * SEQ * DH;
  const unsigned short* khTB = khT + (size_t)bh * DH * SEQ;
  unsigned short* Op = Opart + (size_t)split * MROWS * D_MODEL;
  float* lp = lpart + (size_t)split * BATCH * NH * SEQ;
  s8v aQ[2][2];
#pragma unroll
  for (int g = 0; g < 2; ++g) {
    int q = qb * 128 + w * 32 + g * 16 + l16;
#pragma unroll
    for (int s = 0; s < 2; ++s)
      aQ[g][s] = *(const s8v*)(khB + (size_t)q * DH + s * 32 + quad * 8);
  }
  const s4v vone = {(short)0x3F80, (short)0x3F80, (short)0x3F80, (short)0x3F80};
  f4v accO[2][4] = {};
  f4v accL[2] = {};  // row q = quad*4+r (col-replicated): l-sums via MFMA

  for (int kt8 = 0; kt8 < 8; ++kt8) {
    int key0 = split * 1024 + kt8 * 128;
    // stage lsK (128 keys x 64 d): 1024 chunks, 4 async16/wave
#pragma unroll
    for (int i = 0; i < 4; ++i) {
      int cb = w * 256 + i * 64;
      int ci = cb + lane;
      int row = ci >> 3, c = ci & 7;
      int cs = c ^ (row & 7);
      async16(khB + (size_t)(key0 + row) * DH + cs * 8, &lsK[cb * 8]);
    }
    // stage lsKT (64 d x 128 keys): 1024 chunks, 16-slot swizzle
#pragma unroll
    for (int i = 0; i < 4; ++i) {
      int cb = w * 256 + i * 64;
      int ci = cb + lane;
      int row = ci >> 4, c = ci & 15;
      int cs = c ^ (row & 15);
      async16(khTB + (size_t)row * SEQ + key0 + cs * 8, &lsKT[cb * 8]);
    }
    __builtin_amdgcn_s_waitcnt(0x0f70);  // vmcnt(0)
    __syncthreads();
#pragma unroll
    for (int half = 0; half < 2; ++half) {
      // S^T = K @ Q^T over 64 keys (lane = key within sub-tile)
      f4v accST[2][4] = {};
#pragma unroll
      for (int s = 0; s < 2; ++s) {
#pragma unroll
        for (int tj = 0; tj < 4; ++tj) {
          int key = half * 64 + tj * 16 + l16;
          int c = (s * 4 + quad) ^ (key & 7);
          s8v kf = *(const s8v*)(&lsK[key * 64 + c * 8]);
#pragma unroll
          for (int g = 0; g < 2; ++g)
            accST[g][tj] = __builtin_amdgcn_mfma_f32_16x16x32_bf16(
                kf, aQ[g][s], accST[g][tj], 0, 0, 0);
        }
      }
      // exp in-register -> P A-frags (cvt_pk RNE); l via MFMA; PV from lsKT
#pragma unroll
      for (int tj = 0; tj < 4; ++tj) {
        s4v pf[2];
#pragma unroll
        for (int g = 0; g < 2; ++g) {
          float p0 = xp2(accST[g][tj][0]);
          float p1 = xp2(accST[g][tj][1]);
          float p2 = xp2(accST[g][tj][2]);
          float p3 = xp2(accST[g][tj][3]);
          pf[g] = cvt4(p0, p1, p2, p3);
          accL[g] = mfma16(pf[g], vone, accL[g]);  // l-sum on MFMA pipe
        }
#pragma unroll
        for (int db = 0; db < 4; ++db) {
          int d = db * 16 + l16;
          int ch = (half * 8 + tj * 2 + (quad >> 1)) ^ (d & 15);
          s4v vf = *(const s4v*)(&lsKT[d * 128 + ch * 8 + (quad & 1) * 4]);
#pragma unroll
          for (int g = 0; g < 2; ++g)
            accO[g][db] = mfma16(pf[g], vf, accO[g][db]);
        }
      }
    }
    __syncthreads();
  }
  // epilogue: accL rows = q (quad*4+r), cols replicated -> l16==0 lanes write
  int b = bh >> 4, h = bh & 15;
#pragma unroll
  for (int g = 0; g < 2; ++g) {
    if (l16 == 0) {
#pragma unroll
      for (int r = 0; r < 4; ++r) {
        int q = qb * 128 + w * 32 + g * 16 + quad * 4 + r;
        lp[(size_t)bh * SEQ + q] = accL[g][r];
      }
    }
#pragma unroll
    for (int r = 0; r < 4; ++r) {
      int l = qb * 128 + w * 32 + g * 16 + quad * 4 + r;
#pragma unroll
      for (int db = 0; db < 4; ++db) {
        int d = db * 16 + l16;
        Op[((size_t)(b * SEQ + l)) * D_MODEL + h * DH + d] = f2b(accO[g][db][r]);
      }
    }
  }
}

// ---------------- combine: attn = (O0+O1)/(l0+l1), bf16 partials ------------
// R10: O partials carry the KH_SCALE V-scale; undo with KH_ISCALE here.
__global__ __launch_bounds__(256) void attn_combine(
    const unsigned short* __restrict__ Opart, const float* __restrict__ lpart,
    unsigned short* __restrict__ attn) {
  int row = blockIdx.x;  // b*SEQ + l
  int b = row >> 11, l = row & 2047;
  int c0 = threadIdx.x * 4;
  int h = c0 >> 6;
  size_t lidx = (size_t)(b * NH + h) * SEQ + l;
  float ls = lpart[lidx] + lpart[(size_t)BATCH * NH * SEQ + lidx];
  float inv = KH_ISCALE / ls;
  s4v o0 = *(const s4v*)(Opart + (size_t)row * D_MODEL + c0);
  s4v o1 = *(const s4v*)(Opart + (size_t)MROWS * D_MODEL +
                         (size_t)row * D_MODEL + c0);
  s4v ov;
#pragma unroll
  for (int i = 0; i < 4; ++i)
    ov[i] = (short)f2b((b2f((unsigned short)o0[i]) +
                        b2f((unsigned short)o1[i])) * inv);
  *(s4v*)(attn + (size_t)row * D_MODEL + c0) = ov;
}

// ---------------------------------------------------------------------------
extern "C" void kernel_launch(void* const* d_in, const int* in_sizes, int n_in,
                              void* d_out, int out_size, void* d_ws, size_t ws_size,
                              hipStream_t stream) {
  (void)in_sizes; (void)n_in; (void)out_size;
  const float* x      = (const float*)d_in[0];
  const float* w_attn = (const float*)d_in[1];
  const float* b_attn = (const float*)d_in[2];
  const float* w_proj = (const float*)d_in[3];
  const float* b_proj = (const float*)d_in[4];
  const float* ln1_g  = (const float*)d_in[5];
  const float* ln1_b  = (const float*)d_in[6];
  const float* ln2_g  = (const float*)d_in[7];
  const float* ln2_b  = (const float*)d_in[8];
  const float* w_fc1  = (const float*)d_in[9];
  const float* b_fc1  = (const float*)d_in[10];
  const float* w_fc2  = (const float*)d_in[11];
  const float* b_fc2  = (const float*)d_in[12];

  char* ws = (char*)d_ws;
  float*          x1    = (float*)(ws);                                // 16MB
  unsigned short* hbuf  = (unsigned short*)(ws + (size_t)(16u << 20)); // 8MB
  unsigned short* wT1   = (unsigned short*)(ws + (size_t)(24u << 20)); // 8MB
  unsigned short* wT2   = (unsigned short*)(ws + (size_t)(32u << 20)); // 8MB
  unsigned short* kh    = (unsigned short*)(ws + (size_t)(40u << 20)); // 8MB
  unsigned short* khT   = (unsigned short*)(ws + (size_t)(48u << 20)); // 8MB
  unsigned short* Opart = (unsigned short*)(ws);   // [0,16M) during flash
  float*          lpart = (float*)(ws + (size_t)(16u << 20));  // 512KB, hbuf dead
  unsigned short* fc1o  = kh;  // overlays kh/khT (+tail if unchunked)
  unsigned short* attn  = (unsigned short*)d_out;  // scratch, dead pre-FC2
  float* outf = (float*)d_out;
  bool big_ws = ws_size >= ((size_t)72u << 20);

  dim3 blk(256);
  // 1. h1 = LN1(x)
  hipLaunchKernelGGL(ln_kernel, dim3(MROWS), blk, 0, stream, x, ln1_g, ln1_b, hbuf);
  // 2. wT1 = (w_attn[:, 1024:2048])^T  (only the K slice is ever used)
  hipLaunchKernelGGL(transpose_b<float>, dim3(16, 16, 1), blk, 0, stream,
                     w_attn + 1024, wT1, 3 * D_MODEL, D_MODEL, 0LL, 0LL);
  // 3. kh[b,h,l,d] = (h1 @ w_k + b_k) * KH_SCALE   (BM=64 -> 1024 blocks)
  hipLaunchKernelGGL((gemm_bt<0, false, true, 0, 64, 64>), dim3(16, 64), blk, 0,
                     stream, hbuf, wT1, b_attn + 1024, nullptr, (void*)kh,
                     MROWS, D_MODEL, D_MODEL);
  // 4. khT[b,h,d,l] = transpose(kh) per head
  hipLaunchKernelGGL(transpose_b<unsigned short>, dim3(1, 32, 32), blk, 0, stream,
                     kh, khT, DH, SEQ, (long long)(SEQ * DH), (long long)(DH * SEQ));
  // 5. flash (XCD-local grid) -> bf16 unnormalized partials; combine -> attn
  hipLaunchKernelGGL(flash_k, dim3(2, 32, SEQ / 128), blk, 0, stream,
                     kh, khT, Opart, lpart);
  hipLaunchKernelGGL(attn_combine, dim3(MROWS), blk, 0, stream,
                     Opart, lpart, attn);
  // 6. wT1 = w_proj^T
  hipLaunchKernelGGL(transpose_b<float>, dim3(16, 16, 1), blk, 0, stream,
                     w_proj, wT1, D_MODEL, D_MODEL, 0LL, 0LL);
  // 7. x1 = x + attn @ w_proj + b_proj   (fp32, BM=64 -> 1024 blocks)
  hipLaunchKernelGGL((gemm_bt<2, false, false, 1, 64, 64>), dim3(16, 64), blk, 0,
                     stream, attn, wT1, b_proj, x, (void*)x1,
                     MROWS, D_MODEL, D_MODEL);
  // 8. h2 = LN2(x1)
  hipLaunchKernelGGL(ln_kernel, dim3(MROWS), blk, 0, stream, x1, ln2_g, ln2_b, hbuf);
  // 9. wT1 = w_fc1^T ; wT2 = w_fc2^T
  hipLaunchKernelGGL(transpose_b<float>, dim3(64, 16, 1), blk, 0, stream,
                     w_fc1, wT1, 4 * D_MODEL, D_MODEL, 0LL, 0LL);
  hipLaunchKernelGGL(transpose_b<float>, dim3(16, 64, 1), blk, 0, stream,
                     w_fc2, wT2, D_MODEL, 4 * D_MODEL, 0LL, 0LL);
  // 10. FFN: FC1 BM=128 (2048 blocks); FC2 BM=64 (1024 blocks)
  if (big_ws) {
    hipLaunchKernelGGL((gemm_bt<0, true, false, 0, 128, 64>), dim3(64, 32), blk, 0,
                       stream, hbuf, wT1, b_fc1, nullptr, (void*)fc1o,
                       MROWS, 4 * D_MODEL, D_MODEL);
    hipLaunchKernelGGL((gemm_bt<2, false, false, 1, 64, 64>), dim3(16, 64), blk, 0,
                       stream, fc1o, wT2, b_fc2, x1, (void*)outf,
                       MROWS, D_MODEL, 4 * D_MODEL);
  } else {
    for (int c = 0; c < 2; ++c) {
      const unsigned short* h2c = hbuf + (size_t)c * 2048 * D_MODEL;
      const float* x1c = x1 + (size_t)c * 2048 * D_MODEL;
      float* outc = outf + (size_t)c * 2048 * D_MODEL;
      hipLaunchKernelGGL((gemm_bt<0, true, false, 0, 128, 64>), dim3(64, 16), blk, 0,
                         stream, h2c, wT1, b_fc1, nullptr, (void*)fc1o,
                         2048, 4 * D_MODEL, D_MODEL);
      hipLaunchKernelGGL((gemm_bt<2, false, false, 1, 64, 64>), dim3(16, 32), blk, 0,
                         stream, fc1o, wT2, b_fc2, x1c, (void*)outc,
                         2048, D_MODEL, 4 * D_MODEL);
    }
  }
}